// Round 3
// baseline (3749.375 us; speedup 1.0000x reference)
//
#include <hip/hip_runtime.h>
#include <hip/hip_bf16.h>

typedef unsigned short u16;
typedef __attribute__((ext_vector_type(8)))  short  short8;
typedef __attribute__((ext_vector_type(16))) float  f32x16;

#define MB     256      // batch
#define SRCT   120      // encoder steps
#define DECT   24       // decoder steps
#define NSTEP  (SRCT + DECT)
#define DIN    216      // input dim
#define HDIM   1024     // hidden
#define KX     224      // padded x segment (216 real + 8 zero)
#define KA     1248     // KX + HDIM
#define NGATE  4096     // 4*HDIM
#define OUTD   216
#define KCH    96       // K per LDS chunk (6 mfma k-tiles)
#define NCHUNK 13       // 13*96 = 1248
#define GP     65       // gates LDS pitch (64+1)

__device__ __forceinline__ u16 f2bf(float f) {
    union { float f; unsigned v; } c; c.f = f;
    return (u16)((c.v + 0x7FFFu + ((c.v >> 16) & 1u)) >> 16);
}
__device__ __forceinline__ float sigm(float x)  { return 1.0f / (1.0f + __expf(-x)); }
__device__ __forceinline__ float tanh_(float x) { return 1.0f - 2.0f / (1.0f + __expf(2.0f * x)); }

// ---------------- prep: convert fp32 inputs -> bf16 working buffers ----------------
// ws layout (bf16 unless noted):
//   Abuf  = 2 x [256][1248]          (A = [x_pad | h])
//   C     = [256][1024] fp32         (cell state)
//   Wcat  = [4096][1248]             (cols 0..215 = W_ih, 216..223 = 0, 224.. = W_hh)
//   Wo    = [216][1024]              (W_out)
__global__ void prep_kernel(const float* __restrict__ src,
                            const float* __restrict__ W_ih,
                            const float* __restrict__ W_hh,
                            const float* __restrict__ W_out,
                            u16* __restrict__ Abuf, float* __restrict__ C,
                            u16* __restrict__ Wcat, u16* __restrict__ Wo) {
    const int nW  = NGATE * KA;      // Wcat
    const int nWo = OUTD * HDIM;     // Wo
    const int nA0 = MB * KA;         // Abuf buf0
    const int nP  = MB * 8;          // buf1 pad cols
    const int nC  = MB * HDIM;       // C zero
    const int total = nW + nWo + nA0 + nP + nC;
    for (int i = blockIdx.x * blockDim.x + threadIdx.x; i < total; i += gridDim.x * blockDim.x) {
        if (i < nW) {
            int r = i / KA, col = i % KA;
            u16 v = 0;
            if (col < DIN)      v = f2bf(W_ih[(size_t)r * DIN + col]);
            else if (col >= KX) v = f2bf(W_hh[(size_t)r * HDIM + (col - KX)]);
            Wcat[i] = v;
        } else if (i < nW + nWo) {
            int j = i - nW;
            Wo[j] = f2bf(W_out[j]);
        } else if (i < nW + nWo + nA0) {
            int j = i - nW - nWo;
            int b = j / KA, col = j % KA;
            u16 v = 0;
            if (col < DIN) v = f2bf(src[(size_t)b * (SRCT * DIN) + col]);  // t = 0
            Abuf[j] = v;
        } else if (i < nW + nWo + nA0 + nP) {
            int j = i - nW - nWo - nA0;
            int b = j >> 3, col = DIN + (j & 7);
            Abuf[(size_t)MB * KA + (size_t)b * KA + col] = 0;
        } else {
            C[i - nW - nWo - nA0 - nP] = 0.0f;
        }
    }
}

// ---------------- one LSTM step (GEMM + pointwise) ----------------
// grid 256 = 4 M-tiles x 64 N-tiles. WG tile: [64 M x 64 gate-cols],
// gate-cols = 16 hcols (nj*16..) x {i,f,g,o}. Wave = one 32x32 mfma tile.
// src_t >= 0: also copy next encoder input src[:, src_t, :] into An (bf16).
__global__ void __launch_bounds__(256)
step_kernel(const u16* __restrict__ A, u16* __restrict__ An,
            const float* __restrict__ src, int src_t,
            const u16* __restrict__ Wcat,
            const float* __restrict__ b_ih, const float* __restrict__ b_hh,
            float* __restrict__ C)
{
    // A chunk: [k-octet 12][m 64][8 elems] bf16, double buffered. Conflict-free b128.
    __shared__ u16 Ach[2][12 * 64 * 8];
    __shared__ float G[64 * GP];

    const int bid  = blockIdx.x;
    const int mi   = bid >> 6;     // 0..3
    const int nj   = bid & 63;     // 0..63
    const int m0   = mi * 64;
    const int tid  = threadIdx.x;
    const int w    = tid >> 6;
    const int lane = tid & 63;
    const int msub = w & 1;        // M half of WG tile
    const int nsub = w >> 1;       // N half
    const int l31  = lane & 31;
    const int kg   = lane >> 5;

    // per-lane B row (gate GEMM): col n -> W row
    const int ncol = nsub * 32 + l31;                       // 0..63
    const int gate = ncol >> 4;
    const int rowg = gate * 1024 + nj * 16 + (ncol & 15);   // 0..4095
    const u16* pw  = Wcat + (size_t)rowg * KA;

    const int arow = msub * 32 + l31;   // LDS A row for this lane's mfma A-frag

    f32x16 acc0 = {}; f32x16 acc1 = {};

    // stage chunk 0: 768 octets of 8 elems; thread's s-th seg: flat = tid + s*256
#pragma unroll
    for (int s = 0; s < 3; ++s) {
        int flat = tid + s * 256;
        int cs = flat >> 6, row = flat & 63;
        uint4 v = *(const uint4*)(A + (size_t)(m0 + row) * KA + cs * 8);
        *(uint4*)&Ach[0][cs * 512 + row * 8] = v;
    }
    __syncthreads();

    int p = 0;
    for (int ch = 0; ch < NCHUNK; ++ch) {
        uint4 stg[3];
        if (ch < NCHUNK - 1) {
#pragma unroll
            for (int s = 0; s < 3; ++s) {
                int flat = tid + s * 256;
                int cs = flat >> 6, row = flat & 63;
                stg[s] = *(const uint4*)(A + (size_t)(m0 + row) * KA + (ch + 1) * KCH + cs * 8);
            }
        }
#pragma unroll
        for (int j = 0; j < 6; ++j) {
            const int k = ch * KCH + j * 16;
            short8 af = *(const short8*)&Ach[p][(2 * j + kg) * 512 + arow * 8];
            short8 bf = *(const short8*)(pw + k + kg * 8);
            if (j & 1) acc1 = __builtin_amdgcn_mfma_f32_32x32x16_bf16(af, bf, acc1, 0, 0, 0);
            else       acc0 = __builtin_amdgcn_mfma_f32_32x32x16_bf16(af, bf, acc0, 0, 0, 0);
        }
        if (ch < NCHUNK - 1) {
#pragma unroll
            for (int s = 0; s < 3; ++s) {
                int flat = tid + s * 256;
                int cs = flat >> 6, row = flat & 63;
                *(uint4*)&Ach[p ^ 1][cs * 512 + row * 8] = stg[s];
            }
        }
        __syncthreads();
        p ^= 1;
    }

    // gates -> LDS (C/D layout: col = lane&31, row = (r&3)+8*(r>>2)+4*kg)
#pragma unroll
    for (int r = 0; r < 16; ++r) {
        int grow = (r & 3) + 8 * (r >> 2) + 4 * kg;
        G[(msub * 32 + grow) * GP + nsub * 32 + l31] = acc0[r] + acc1[r];
    }
    __syncthreads();

    // pointwise LSTM cell; c fp32 in global ws, h -> bf16 into next A buffer
    const int pm = tid & 63;
    const int pb = (tid >> 6) * 4;
#pragma unroll
    for (int e = 0; e < 4; ++e) {
        int hc = pb + e;                  // 0..15 local hcol
        int hcg = nj * 16 + hc;           // global hcol
        float gi = G[pm * GP + hc]      + b_ih[hcg]        + b_hh[hcg];
        float gf = G[pm * GP + 16 + hc] + b_ih[1024 + hcg] + b_hh[1024 + hcg];
        float gg = G[pm * GP + 32 + hc] + b_ih[2048 + hcg] + b_hh[2048 + hcg];
        float go = G[pm * GP + 48 + hc] + b_ih[3072 + hcg] + b_hh[3072 + hcg];
        size_t ci = (size_t)(m0 + pm) * HDIM + hcg;
        float c  = sigm(gf) * C[ci] + sigm(gi) * tanh_(gg);
        C[ci] = c;
        float h  = sigm(go) * tanh_(c);
        An[(size_t)(m0 + pm) * KA + KX + hcg] = f2bf(h);
    }

    // encoder: copy next x = src[:, src_t, :] into An (fp32 -> bf16)
    if (src_t >= 0 && nj == 0) {
        for (int flat = tid; flat < 64 * DIN; flat += 256) {
            int r = flat / DIN, cc = flat % DIN;
            An[(size_t)(m0 + r) * KA + cc] =
                f2bf(src[(size_t)(m0 + r) * (SRCT * DIN) + src_t * DIN + cc]);
        }
    }
}

// ---------------- decoder projection: out = h @ W_out^T + b_out ----------------
// 14 blocks x 4 waves = 56 tiles = 8 Mtiles x 7 Ntiles (216 padded to 224).
// Writes d_out[:, d, :] (fp32) and next decoder x (bf16) into An cols 0..215.
__global__ void __launch_bounds__(256)
out_kernel(const u16* __restrict__ An, const u16* __restrict__ Wo,
           const float* __restrict__ b_out, float* __restrict__ dout, int d)
{
    const int tid  = threadIdx.x;
    const int w    = tid >> 6;
    const int lane = tid & 63;
    const int l31  = lane & 31;
    const int kg   = lane >> 5;

    const int tile = blockIdx.x * 4 + w;   // 0..55
    const int mt = tile & 7;
    const int nt = tile >> 3;
    const int am = mt * 32 + l31;
    const int bn = nt * 32 + l31;
    const int brow = (bn < OUTD) ? bn : (OUTD - 1);
    f32x16 oa0 = {}; f32x16 oa1 = {};
    const u16* ah = An + (size_t)am * KA + KX + kg * 8;
    const u16* bw = Wo + (size_t)brow * HDIM + kg * 8;
#pragma unroll 4
    for (int kt = 0; kt < 64; ++kt) {
        short8 af = *(const short8*)(ah + kt * 16);
        short8 bf = *(const short8*)(bw + kt * 16);
        if (kt & 1) oa1 = __builtin_amdgcn_mfma_f32_32x32x16_bf16(af, bf, oa1, 0, 0, 0);
        else        oa0 = __builtin_amdgcn_mfma_f32_32x32x16_bf16(af, bf, oa0, 0, 0, 0);
    }
    if (bn < OUTD) {
        float bo = b_out[bn];
        u16* Anx = (u16*)An;   // also feeds next decoder x
#pragma unroll
        for (int r = 0; r < 16; ++r) {
            int grow = (r & 3) + 8 * (r >> 2) + 4 * kg;
            int mm = mt * 32 + grow;
            float v = oa0[r] + oa1[r] + bo;
            dout[(size_t)mm * (DECT * OUTD) + d * OUTD + bn] = v;
            Anx[(size_t)mm * KA + bn] = f2bf(v);
        }
    }
}

extern "C" void kernel_launch(void* const* d_in, const int* in_sizes, int n_in,
                              void* d_out, int out_size, void* d_ws, size_t ws_size,
                              hipStream_t stream) {
    const float* src   = (const float*)d_in[0];
    // d_in[1] = tgt (unused in eval forward)
    const float* W_ih  = (const float*)d_in[2];
    const float* W_hh  = (const float*)d_in[3];
    const float* b_ih  = (const float*)d_in[4];
    const float* b_hh  = (const float*)d_in[5];
    const float* W_out = (const float*)d_in[6];
    const float* b_out = (const float*)d_in[7];
    float* out = (float*)d_out;

    char* ws = (char*)d_ws;
    u16*   Abuf = (u16*)ws;                                   // 2*256*1248*2 = 1,277,952 B
    float* C    = (float*)(ws + 1277952);                     // 256*1024*4   = 1,048,576 B
    u16*   Wcat = (u16*)(ws + 1277952 + 1048576);             // 4096*1248*2  = 10,223,616 B
    u16*   Wo   = (u16*)(ws + 1277952 + 1048576 + 10223616);  // 216*1024*2   = 442,368 B

    hipLaunchKernelGGL(prep_kernel, dim3(1024), dim3(256), 0, stream,
                       src, W_ih, W_hh, W_out, Abuf, C, Wcat, Wo);

    for (int t = 0; t < NSTEP; ++t) {
        const u16* A = Abuf + (size_t)(t & 1) * MB * KA;
        u16*      An = Abuf + (size_t)((t + 1) & 1) * MB * KA;
        int src_t = (t < SRCT) ? ((t + 1 < SRCT) ? t + 1 : SRCT - 1) : -1;
        hipLaunchKernelGGL(step_kernel, dim3(256), dim3(256), 0, stream,
                           A, An, src, src_t, Wcat, b_ih, b_hh, C);
        if (t >= SRCT) {
            hipLaunchKernelGGL(out_kernel, dim3(14), dim3(256), 0, stream,
                               An, Wo, b_out, out, t - SRCT);
        }
    }
}